// Round 1
// baseline (983.027 us; speedup 1.0000x reference)
//
#include <hip/hip_runtime.h>

#define T_ 1024
#define H_ 2048
#define I_ 3200
#define E_ 8

typedef float f32x4 __attribute__((ext_vector_type(4)));
typedef float fvec4 __attribute__((ext_vector_type(4)));
typedef __bf16 bf16x8 __attribute__((ext_vector_type(8)));
typedef unsigned short u16x8 __attribute__((ext_vector_type(8)));
typedef unsigned short u16x4 __attribute__((ext_vector_type(4)));

typedef const __attribute__((address_space(1))) void* gp1_t;
typedef __attribute__((address_space(3))) void* sp3_t;

// ---- ws layout (bytes) ----
// 0      : cnt[8]            (zeroed each launch)
// 64     : base[16]          (prefix of 128-padded counts)
// 128    : tok_list[8*1024]  int
// 32896  : gate_list[8*1024] float
// 65664  : xb  [1024*2048]   bf16 (4 MB)
// 4259968: actb[3072*3200]   bf16 (~18.75 MB)
#define WS_TOK   128
#define WS_GATE  32896
#define WS_XB    65664
#define WS_ACT   4259968

__device__ __forceinline__ unsigned short f2bf(float f) {
  unsigned u = __builtin_bit_cast(unsigned, f);
  u += 0x7FFFu + ((u >> 16) & 1u);           // round-to-nearest-even
  return (unsigned short)(u >> 16);
}

// ---------------- x f32 -> bf16 ----------------
__global__ __launch_bounds__(256) void cvt_x_kernel(const float* __restrict__ x,
                                                    unsigned short* __restrict__ xb) {
  int i = blockIdx.x * 256 + threadIdx.x;    // 4 elems each, grid covers T*H/4
  fvec4 v = reinterpret_cast<const fvec4*>(x)[i];
  u16x4 o;
  o[0] = f2bf(v[0]); o[1] = f2bf(v[1]); o[2] = f2bf(v[2]); o[3] = f2bf(v[3]);
  reinterpret_cast<u16x4*>(xb)[i] = o;
}

// ---------------- router + sparsemixer + list build ----------------
__global__ __launch_bounds__(256) void router_kernel(const float* __restrict__ x,
                                                     const float* __restrict__ gw,
                                                     int* __restrict__ cnt,
                                                     int* __restrict__ tok,
                                                     float* __restrict__ gate) {
  const int lane = threadIdx.x & 63;
  const int wv = threadIdx.x >> 6;
  const int t = blockIdx.x * 4 + wv;         // one wave per token

  float xr[32];
  const float* xp = x + (size_t)t * H_;
#pragma unroll
  for (int j = 0; j < 32; j++) xr[j] = xp[j * 64 + lane];

  float s[E_];
#pragma unroll
  for (int e = 0; e < E_; e++) {
    const float* gp = gw + (size_t)e * H_;
    float p = 0.f;
#pragma unroll
    for (int j = 0; j < 32; j++) p = fmaf(xr[j], gp[j * 64 + lane], p);
#pragma unroll
    for (int off = 32; off > 0; off >>= 1) p += __shfl_xor(p, off);
    s[e] = p;
  }

  // top-1 (first-occurrence argmax)
  float max1 = s[0]; int i1 = 0;
#pragma unroll
  for (int e = 1; e < E_; e++) if (s[e] > max1) { max1 = s[e]; i1 = e; }
  float den1 = 0.f;
#pragma unroll
  for (int e = 0; e < E_; e++) {
    float factor = fmaxf(fabsf(s[e]), max1);
    if ((max1 - s[e]) <= 0.02f * factor) den1 += expf(s[e] - max1);
  }
  float mult1 = 1.f / den1;

  // top-2 over masked scores
  float max2 = -INFINITY; int i2 = 0;
#pragma unroll
  for (int e = 0; e < E_; e++) if (e != i1 && s[e] > max2) { max2 = s[e]; i2 = e; }
  float den2 = 0.f;
#pragma unroll
  for (int e = 0; e < E_; e++) {
    if (e == i1) continue;
    float factor = fmaxf(fabsf(s[e]), max2);
    if ((max2 - s[e]) <= 0.02f * factor) den2 += expf(s[e] - max2);
  }
  float mult2 = 1.f / den2;

  if (lane == 0) {
    int p1 = atomicAdd(&cnt[i1], 1); tok[i1 * T_ + p1] = t; gate[i1 * T_ + p1] = mult1;
    int p2 = atomicAdd(&cnt[i2], 1); tok[i2 * T_ + p2] = t; gate[i2 * T_ + p2] = mult2;
  }
}

// ---------------- prefix of 128-padded counts ----------------
__global__ void prefix_kernel(const int* __restrict__ cnt, int* __restrict__ base) {
  if (threadIdx.x == 0 && blockIdx.x == 0) {
    int a = 0;
    for (int e = 0; e < E_; e++) { base[e] = a; a += (cnt[e] + 127) & ~127; }
    base[E_] = a;
  }
}

// ---------------- FFN1: act = silu(x@w1^T) * (x@w3^T), grouped ----------------
__global__ __launch_bounds__(256, 2) void ffn1_kernel(
    const unsigned short* __restrict__ xb, const float* __restrict__ w1,
    const float* __restrict__ w3, const int* __restrict__ cnt,
    const int* __restrict__ base, const int* __restrict__ tokl,
    unsigned short* __restrict__ actb) {
  const int e = blockIdx.z;
  const int count = cnt[e];
  const int m0 = blockIdx.x * 128;           // token rows within expert list
  if (m0 >= count) return;
  const int n0 = blockIdx.y * 128;           // I columns
  const int tid = threadIdx.x;
  const int lane = tid & 63, wv = tid >> 6;
  const int wm = wv >> 1, wn = wv & 1;

  __shared__ int tokS[128];
  __shared__ unsigned short As[128 * 64];
  __shared__ unsigned short B1s[128 * 64];
  __shared__ unsigned short B3s[128 * 64];

  if (tid < 128) {
    int r = m0 + tid;
    tokS[tid] = (r < count) ? tokl[e * T_ + r] : tokl[e * T_ + count - 1];
  }
  __syncthreads();

  const unsigned short* aSrc[4];
#pragma unroll
  for (int i = 0; i < 4; i++) {
    int row = wv * 32 + i * 8 + (lane >> 3);
    aSrc[i] = xb + (size_t)tokS[row] * H_ + ((lane & 7) * 8);
  }
  const int brow = tid >> 1, bc0 = (tid & 1) * 32;
  const float* b1p = w1 + ((size_t)e * I_ + n0 + brow) * H_ + bc0;
  const float* b3p = w3 + ((size_t)e * I_ + n0 + brow) * H_ + bc0;

  f32x4 acc1[4][4], acc3[4][4];
#pragma unroll
  for (int mi = 0; mi < 4; mi++)
#pragma unroll
    for (int ni = 0; ni < 4; ni++) {
      acc1[mi][ni] = (f32x4){0.f, 0.f, 0.f, 0.f};
      acc3[mi][ni] = (f32x4){0.f, 0.f, 0.f, 0.f};
    }

  for (int ks = 0; ks < H_ / 64; ks++) {
    // stage A (bf16, direct to LDS)
#pragma unroll
    for (int i = 0; i < 4; i++) {
      __builtin_amdgcn_global_load_lds((gp1_t)(aSrc[i]), (sp3_t)(&As[(wv * 32 + i * 8) * 64]),
                                       16, 0, 0);
      aSrc[i] += 64;
    }
    // stage B1/B3 (f32 -> bf16 via regs)
#pragma unroll
    for (int j = 0; j < 4; j++) {
      fvec4 lo = *reinterpret_cast<const fvec4*>(b1p + j * 8);
      fvec4 hi = *reinterpret_cast<const fvec4*>(b1p + j * 8 + 4);
      u16x8 v;
      v[0] = f2bf(lo[0]); v[1] = f2bf(lo[1]); v[2] = f2bf(lo[2]); v[3] = f2bf(lo[3]);
      v[4] = f2bf(hi[0]); v[5] = f2bf(hi[1]); v[6] = f2bf(hi[2]); v[7] = f2bf(hi[3]);
      *reinterpret_cast<u16x8*>(&B1s[brow * 64 + bc0 + j * 8]) = v;
    }
#pragma unroll
    for (int j = 0; j < 4; j++) {
      fvec4 lo = *reinterpret_cast<const fvec4*>(b3p + j * 8);
      fvec4 hi = *reinterpret_cast<const fvec4*>(b3p + j * 8 + 4);
      u16x8 v;
      v[0] = f2bf(lo[0]); v[1] = f2bf(lo[1]); v[2] = f2bf(lo[2]); v[3] = f2bf(lo[3]);
      v[4] = f2bf(hi[0]); v[5] = f2bf(hi[1]); v[6] = f2bf(hi[2]); v[7] = f2bf(hi[3]);
      *reinterpret_cast<u16x8*>(&B3s[brow * 64 + bc0 + j * 8]) = v;
    }
    b1p += 64; b3p += 64;
    __syncthreads();

#pragma unroll
    for (int kk = 0; kk < 2; kk++) {
      bf16x8 a[4];
#pragma unroll
      for (int mi = 0; mi < 4; mi++)
        a[mi] = *reinterpret_cast<const bf16x8*>(
            &As[(wm * 64 + mi * 16 + (lane & 15)) * 64 + kk * 32 + (lane >> 4) * 8]);
#pragma unroll
      for (int ni = 0; ni < 4; ni++) {
        const int boff = (wn * 64 + ni * 16 + (lane & 15)) * 64 + kk * 32 + (lane >> 4) * 8;
        bf16x8 b1 = *reinterpret_cast<const bf16x8*>(&B1s[boff]);
#pragma unroll
        for (int mi = 0; mi < 4; mi++)
          acc1[mi][ni] = __builtin_amdgcn_mfma_f32_16x16x32_bf16(a[mi], b1, acc1[mi][ni], 0, 0, 0);
        bf16x8 b3 = *reinterpret_cast<const bf16x8*>(&B3s[boff]);
#pragma unroll
        for (int mi = 0; mi < 4; mi++)
          acc3[mi][ni] = __builtin_amdgcn_mfma_f32_16x16x32_bf16(a[mi], b3, acc3[mi][ni], 0, 0, 0);
      }
    }
    __syncthreads();
  }

  const int ab = base[e];
#pragma unroll
  for (int mi = 0; mi < 4; mi++)
#pragma unroll
    for (int ni = 0; ni < 4; ni++) {
      f32x4 v1 = acc1[mi][ni], v3 = acc3[mi][ni];
#pragma unroll
      for (int j = 0; j < 4; j++) {
        float h1 = v1[j];
        float a = (h1 / (1.f + __expf(-h1))) * v3[j];   // silu(h1)*h3
        int row = wm * 64 + mi * 16 + (lane >> 4) * 4 + j;
        int col = n0 + wn * 64 + ni * 16 + (lane & 15);
        actb[(size_t)(ab + m0 + row) * I_ + col] = f2bf(a);
      }
    }
}

// ---------------- FFN2: out[tok] += gate * act@w2^T ----------------
__global__ __launch_bounds__(256, 2) void ffn2_kernel(
    const unsigned short* __restrict__ actb, const float* __restrict__ w2,
    const int* __restrict__ cnt, const int* __restrict__ base,
    const int* __restrict__ tokl, const float* __restrict__ gatel,
    float* __restrict__ out) {
  const int e = blockIdx.z;
  const int count = cnt[e];
  const int m0 = blockIdx.x * 128;
  if (m0 >= count) return;
  const int n0 = blockIdx.y * 128;           // H columns
  const int tid = threadIdx.x;
  const int lane = tid & 63, wv = tid >> 6;
  const int wm = wv >> 1, wn = wv & 1;

  __shared__ int tokS[128];
  __shared__ float gateS[128];
  __shared__ unsigned short As[128 * 64];
  __shared__ unsigned short Bs[128 * 64];

  if (tid < 128) {
    int r = m0 + tid;
    bool vld = r < count;
    tokS[tid] = vld ? tokl[e * T_ + r] : 0;
    gateS[tid] = vld ? gatel[e * T_ + r] : 0.f;
  }
  __syncthreads();

  const int ab = base[e];
  const unsigned short* aSrc[4];
#pragma unroll
  for (int i = 0; i < 4; i++) {
    int row = wv * 32 + i * 8 + (lane >> 3);
    aSrc[i] = actb + (size_t)(ab + m0 + row) * I_ + ((lane & 7) * 8);
  }
  const int brow = tid >> 1, bc0 = (tid & 1) * 32;
  const float* bp = w2 + ((size_t)e * H_ + n0 + brow) * I_ + bc0;

  f32x4 acc[4][4];
#pragma unroll
  for (int mi = 0; mi < 4; mi++)
#pragma unroll
    for (int ni = 0; ni < 4; ni++) acc[mi][ni] = (f32x4){0.f, 0.f, 0.f, 0.f};

  for (int ks = 0; ks < I_ / 64; ks++) {     // 50 steps
#pragma unroll
    for (int i = 0; i < 4; i++) {
      __builtin_amdgcn_global_load_lds((gp1_t)(aSrc[i]), (sp3_t)(&As[(wv * 32 + i * 8) * 64]),
                                       16, 0, 0);
      aSrc[i] += 64;
    }
#pragma unroll
    for (int j = 0; j < 4; j++) {
      fvec4 lo = *reinterpret_cast<const fvec4*>(bp + j * 8);
      fvec4 hi = *reinterpret_cast<const fvec4*>(bp + j * 8 + 4);
      u16x8 v;
      v[0] = f2bf(lo[0]); v[1] = f2bf(lo[1]); v[2] = f2bf(lo[2]); v[3] = f2bf(lo[3]);
      v[4] = f2bf(hi[0]); v[5] = f2bf(hi[1]); v[6] = f2bf(hi[2]); v[7] = f2bf(hi[3]);
      *reinterpret_cast<u16x8*>(&Bs[brow * 64 + bc0 + j * 8]) = v;
    }
    bp += 64;
    __syncthreads();

#pragma unroll
    for (int kk = 0; kk < 2; kk++) {
      bf16x8 a[4];
#pragma unroll
      for (int mi = 0; mi < 4; mi++)
        a[mi] = *reinterpret_cast<const bf16x8*>(
            &As[(wm * 64 + mi * 16 + (lane & 15)) * 64 + kk * 32 + (lane >> 4) * 8]);
#pragma unroll
      for (int ni = 0; ni < 4; ni++) {
        bf16x8 b = *reinterpret_cast<const bf16x8*>(
            &Bs[(wn * 64 + ni * 16 + (lane & 15)) * 64 + kk * 32 + (lane >> 4) * 8]);
#pragma unroll
        for (int mi = 0; mi < 4; mi++)
          acc[mi][ni] = __builtin_amdgcn_mfma_f32_16x16x32_bf16(a[mi], b, acc[mi][ni], 0, 0, 0);
      }
    }
    __syncthreads();
  }

#pragma unroll
  for (int mi = 0; mi < 4; mi++)
#pragma unroll
    for (int ni = 0; ni < 4; ni++)
#pragma unroll
      for (int j = 0; j < 4; j++) {
        int row = wm * 64 + mi * 16 + (lane >> 4) * 4 + j;
        if (m0 + row < count) {
          int tokv = tokS[row];
          float g = gateS[row];
          int col = n0 + wn * 64 + ni * 16 + (lane & 15);
          atomicAdd(&out[(size_t)tokv * H_ + col], g * acc[mi][ni][j]);
        }
      }
}

extern "C" void kernel_launch(void* const* d_in, const int* in_sizes, int n_in,
                              void* d_out, int out_size, void* d_ws, size_t ws_size,
                              hipStream_t stream) {
  const float* x  = (const float*)d_in[0];
  const float* gw = (const float*)d_in[1];
  const float* w1 = (const float*)d_in[2];
  const float* w3 = (const float*)d_in[3];
  const float* w2 = (const float*)d_in[4];
  float* out = (float*)d_out;
  char* ws = (char*)d_ws;

  int* cnt = (int*)ws;
  int* base = (int*)(ws + 64);
  int* tokl = (int*)(ws + WS_TOK);
  float* gatel = (float*)(ws + WS_GATE);
  unsigned short* xb = (unsigned short*)(ws + WS_XB);
  unsigned short* actb = (unsigned short*)(ws + WS_ACT);

  (void)hipMemsetAsync(d_out, 0, (size_t)T_ * H_ * sizeof(float), stream);
  (void)hipMemsetAsync(ws, 0, 64, stream);

  cvt_x_kernel<<<(T_ * H_ / 4 + 255) / 256, 256, 0, stream>>>(x, xb);
  router_kernel<<<T_ / 4, 256, 0, stream>>>(x, gw, cnt, tokl, gatel);
  prefix_kernel<<<1, 64, 0, stream>>>(cnt, base);
  ffn1_kernel<<<dim3(T_ / 128, I_ / 128, E_), 256, 0, stream>>>(xb, w1, w3, cnt, base, tokl, actb);
  ffn2_kernel<<<dim3(T_ / 128, H_ / 128, E_), 256, 0, stream>>>(actb, w2, cnt, base, tokl, gatel, out);
}

// Round 2
// 351.952 us; speedup vs baseline: 2.7931x; 2.7931x over previous
//
#include <hip/hip_runtime.h>

#define T_ 1024
#define H_ 2048
#define I_ 3200
#define E_ 8

typedef float fvec4 __attribute__((ext_vector_type(4)));
typedef float f32x4 __attribute__((ext_vector_type(4)));
typedef __bf16 bf16x8 __attribute__((ext_vector_type(8)));
typedef unsigned short u16x8 __attribute__((ext_vector_type(8)));
typedef unsigned short u16x4 __attribute__((ext_vector_type(4)));

typedef const __attribute__((address_space(1))) void* gp1_t;
typedef __attribute__((address_space(3))) void* sp3_t;

// ---- ws layout (bytes) ----
#define WS_TOK   128
#define WS_GATE  32896
#define WS_XB    65664
#define WS_ACT   4259968   // 3328 rows x 3200 bf16 = 21.3 MB (slack rows for OOB-safe A reads)

__device__ __forceinline__ unsigned short f2bf(float f) {
  unsigned u = __builtin_bit_cast(unsigned, f);
  u += 0x7FFFu + ((u >> 16) & 1u);           // round-to-nearest-even
  return (unsigned short)(u >> 16);
}

// ---------------- x f32 -> bf16 ----------------
__global__ __launch_bounds__(256) void cvt_x_kernel(const float* __restrict__ x,
                                                    unsigned short* __restrict__ xb) {
  int i = blockIdx.x * 256 + threadIdx.x;
  fvec4 v = reinterpret_cast<const fvec4*>(x)[i];
  u16x4 o;
  o[0] = f2bf(v[0]); o[1] = f2bf(v[1]); o[2] = f2bf(v[2]); o[3] = f2bf(v[3]);
  reinterpret_cast<u16x4*>(xb)[i] = o;
}

// ---------------- router + sparsemixer + list build ----------------
__global__ __launch_bounds__(256) void router_kernel(const float* __restrict__ x,
                                                     const float* __restrict__ gw,
                                                     int* __restrict__ cnt,
                                                     int* __restrict__ tok,
                                                     float* __restrict__ gate) {
  const int lane = threadIdx.x & 63;
  const int wv = threadIdx.x >> 6;
  const int t = blockIdx.x * 4 + wv;

  float xr[32];
  const float* xp = x + (size_t)t * H_;
#pragma unroll
  for (int j = 0; j < 32; j++) xr[j] = xp[j * 64 + lane];

  float s[E_];
#pragma unroll
  for (int e = 0; e < E_; e++) {
    const float* gp = gw + (size_t)e * H_;
    float p = 0.f;
#pragma unroll
    for (int j = 0; j < 32; j++) p = fmaf(xr[j], gp[j * 64 + lane], p);
#pragma unroll
    for (int off = 32; off > 0; off >>= 1) p += __shfl_xor(p, off);
    s[e] = p;
  }

  float max1 = s[0]; int i1 = 0;
#pragma unroll
  for (int e = 1; e < E_; e++) if (s[e] > max1) { max1 = s[e]; i1 = e; }
  float den1 = 0.f;
#pragma unroll
  for (int e = 0; e < E_; e++) {
    float factor = fmaxf(fabsf(s[e]), max1);
    if ((max1 - s[e]) <= 0.02f * factor) den1 += expf(s[e] - max1);
  }
  float mult1 = 1.f / den1;

  float max2 = -INFINITY; int i2 = 0;
#pragma unroll
  for (int e = 0; e < E_; e++) if (e != i1 && s[e] > max2) { max2 = s[e]; i2 = e; }
  float den2 = 0.f;
#pragma unroll
  for (int e = 0; e < E_; e++) {
    if (e == i1) continue;
    float factor = fmaxf(fabsf(s[e]), max2);
    if ((max2 - s[e]) <= 0.02f * factor) den2 += expf(s[e] - max2);
  }
  float mult2 = 1.f / den2;

  if (lane == 0) {
    int p1 = atomicAdd(&cnt[i1], 1); tok[i1 * T_ + p1] = t; gate[i1 * T_ + p1] = mult1;
    int p2 = atomicAdd(&cnt[i2], 1); tok[i2 * T_ + p2] = t; gate[i2 * T_ + p2] = mult2;
  }
}

// ---------------- prefix of 128-padded counts ----------------
__global__ void prefix_kernel(const int* __restrict__ cnt, int* __restrict__ base) {
  if (threadIdx.x == 0 && blockIdx.x == 0) {
    int a = 0;
    for (int e = 0; e < E_; e++) { base[e] = a; a += (cnt[e] + 127) & ~127; }
    base[E_] = a;
  }
}

// ---------------- FFN1: BM=256 (2 m-tiles), BN=64, BK=64, async pipeline ----------------
__global__ __launch_bounds__(256, 2) void ffn1_kernel(
    const unsigned short* __restrict__ xb, const float* __restrict__ w1,
    const float* __restrict__ w3, const int* __restrict__ cnt,
    const int* __restrict__ base, const int* __restrict__ tokl,
    unsigned short* __restrict__ actb) {
  const int e = blockIdx.z;
  const int ab = base[e];
  const int padcnt = base[e + 1] - ab;
  const int m_base = blockIdx.y * 256;
  if (m_base >= padcnt) return;
  const int count = cnt[e];
  const int n0 = blockIdx.x * 64;
  const int tid = threadIdx.x;
  const int lane = tid & 63, wv = tid >> 6;
  const int wm = wv >> 1, wn = wv & 1;

  __shared__ unsigned short Ash[2][256 * 64];   // 64 KiB, double-buffered
  __shared__ unsigned short B1s[64 * 64];       // 8 KiB
  __shared__ unsigned short B3s[64 * 64];       // 8 KiB

  // A gather sources, pre-swizzled global column (st-16 XOR) so linear LDS = swizzled
  const unsigned short* aSrc[8];
  const int colg = ((lane & 7) ^ ((lane >> 3) & 7)) * 8;  // bf16 element offset
#pragma unroll
  for (int i = 0; i < 8; ++i) {
    int r = m_base + wv * 64 + i * 8 + (lane >> 3);
    if (r >= count) r = count - 1;
    aSrc[i] = xb + (size_t)tokl[e * T_ + r] * H_ + colg;
  }
  const int brow = tid >> 2;
  const int bc = (tid & 3) * 16;
  const float* b1p = w1 + ((size_t)e * I_ + n0 + brow) * H_ + bc;
  const float* b3p = w3 + ((size_t)e * I_ + n0 + brow) * H_ + bc;

  // prologue: issue tile 0 (A -> LDS buf0, B -> regs)
#pragma unroll
  for (int i = 0; i < 8; ++i) {
    __builtin_amdgcn_global_load_lds((gp1_t)aSrc[i], (sp3_t)&Ash[0][(wv * 64 + i * 8) * 64], 16, 0, 0);
    aSrc[i] += 64;
  }
  fvec4 r1[4], r3[4];
#pragma unroll
  for (int j = 0; j < 4; ++j) { r1[j] = *(const fvec4*)(b1p + j * 4); r3[j] = *(const fvec4*)(b3p + j * 4); }
  b1p += 64; b3p += 64;

  f32x4 acc1[2][4][2], acc3[2][4][2];
#pragma unroll
  for (int mt = 0; mt < 2; ++mt)
#pragma unroll
    for (int mi = 0; mi < 4; ++mi)
#pragma unroll
      for (int ni = 0; ni < 2; ++ni) {
        acc1[mt][mi][ni] = (f32x4){0.f, 0.f, 0.f, 0.f};
        acc3[mt][mi][ni] = (f32x4){0.f, 0.f, 0.f, 0.f};
      }

  const int swz = brow & 7;
  const int c0 = (tid & 3) * 2;
  char* pB1 = (char*)B1s + brow * 128;
  char* pB3 = (char*)B3s + brow * 128;

  for (int t = 0; t < H_ / 64; ++t) {
    const int cur = t & 1;
    asm volatile("s_waitcnt vmcnt(0)" ::: "memory");
    // convert + swizzled write of B tiles (tile t)
#pragma unroll
    for (int c = 0; c < 2; ++c) {
      fvec4 lo = r1[c * 2], hi = r1[c * 2 + 1];
      u16x8 v;
      v[0] = f2bf(lo[0]); v[1] = f2bf(lo[1]); v[2] = f2bf(lo[2]); v[3] = f2bf(lo[3]);
      v[4] = f2bf(hi[0]); v[5] = f2bf(hi[1]); v[6] = f2bf(hi[2]); v[7] = f2bf(hi[3]);
      *(u16x8*)(pB1 + (((c0 + c) ^ swz) << 4)) = v;
      fvec4 lo3 = r3[c * 2], hi3 = r3[c * 2 + 1];
      u16x8 w;
      w[0] = f2bf(lo3[0]); w[1] = f2bf(lo3[1]); w[2] = f2bf(lo3[2]); w[3] = f2bf(lo3[3]);
      w[4] = f2bf(hi3[0]); w[5] = f2bf(hi3[1]); w[6] = f2bf(hi3[2]); w[7] = f2bf(hi3[3]);
      *(u16x8*)(pB3 + (((c0 + c) ^ swz) << 4)) = w;
    }
    __syncthreads();
    if (t + 1 < H_ / 64) {   // issue tile t+1 while computing tile t
#pragma unroll
      for (int i = 0; i < 8; ++i) {
        __builtin_amdgcn_global_load_lds((gp1_t)aSrc[i],
            (sp3_t)&Ash[cur ^ 1][(wv * 64 + i * 8) * 64], 16, 0, 0);
        aSrc[i] += 64;
      }
#pragma unroll
      for (int j = 0; j < 4; ++j) { r1[j] = *(const fvec4*)(b1p + j * 4); r3[j] = *(const fvec4*)(b3p + j * 4); }
      b1p += 64; b3p += 64;
    }
    const unsigned short* Ac = Ash[cur];
#pragma unroll
    for (int kk = 0; kk < 2; ++kk) {
      const int c16 = kk * 4 + (lane >> 4);
      bf16x8 b1f[2], b3f[2];
#pragma unroll
      for (int ni = 0; ni < 2; ++ni) {
        int br_ = wn * 32 + ni * 16 + (lane & 15);
        b1f[ni] = *(const bf16x8*)((const char*)B1s + br_ * 128 + ((c16 ^ (br_ & 7)) << 4));
        b3f[ni] = *(const bf16x8*)((const char*)B3s + br_ * 128 + ((c16 ^ (br_ & 7)) << 4));
      }
#pragma unroll
      for (int mt = 0; mt < 2; ++mt) {
        bf16x8 af[4];
#pragma unroll
        for (int mi = 0; mi < 4; ++mi) {
          int ar = mt * 128 + wm * 64 + mi * 16 + (lane & 15);
          af[mi] = *(const bf16x8*)((const char*)Ac + ar * 128 + ((c16 ^ (ar & 7)) << 4));
        }
#pragma unroll
        for (int mi = 0; mi < 4; ++mi)
#pragma unroll
          for (int ni = 0; ni < 2; ++ni) {
            acc1[mt][mi][ni] = __builtin_amdgcn_mfma_f32_16x16x32_bf16(af[mi], b1f[ni], acc1[mt][mi][ni], 0, 0, 0);
            acc3[mt][mi][ni] = __builtin_amdgcn_mfma_f32_16x16x32_bf16(af[mi], b3f[ni], acc3[mt][mi][ni], 0, 0, 0);
          }
      }
    }
    __syncthreads();
  }

  const int row_lim = padcnt - m_base;
#pragma unroll
  for (int mt = 0; mt < 2; ++mt)
#pragma unroll
    for (int mi = 0; mi < 4; ++mi)
#pragma unroll
      for (int ni = 0; ni < 2; ++ni) {
        f32x4 v1 = acc1[mt][mi][ni], v3 = acc3[mt][mi][ni];
#pragma unroll
        for (int j = 0; j < 4; ++j) {
          int row = mt * 128 + wm * 64 + mi * 16 + (lane >> 4) * 4 + j;
          if (row < row_lim) {
            float h1 = v1[j];
            float a = (h1 / (1.f + __expf(-h1))) * v3[j];
            actb[(size_t)(ab + m_base + row) * I_ + n0 + wn * 32 + ni * 16 + (lane & 15)] = f2bf(a);
          }
        }
      }
}

// ---------------- FFN2: BM=256, BN=64, BK=64, async pipeline ----------------
__global__ __launch_bounds__(256, 2) void ffn2_kernel(
    const unsigned short* __restrict__ actb, const float* __restrict__ w2,
    const int* __restrict__ cnt, const int* __restrict__ base,
    const int* __restrict__ tokl, const float* __restrict__ gatel,
    float* __restrict__ out) {
  const int e = blockIdx.z;
  const int count = cnt[e];
  const int m_base = blockIdx.y * 256;
  if (m_base >= count) return;
  const int ab = base[e];
  const int n0 = blockIdx.x * 64;
  const int tid = threadIdx.x;
  const int lane = tid & 63, wv = tid >> 6;
  const int wm = wv >> 1, wn = wv & 1;

  __shared__ unsigned short Ash[2][256 * 64];   // 64 KiB
  __shared__ unsigned short Bs[64 * 64];        // 8 KiB
  __shared__ int tokS[256];
  __shared__ float gateS[256];

  if (tid < 256) {
    int r = m_base + tid;
    bool vld = r < count;
    tokS[tid] = vld ? tokl[e * T_ + r] : 0;
    gateS[tid] = vld ? gatel[e * T_ + r] : 0.f;
  }

  const unsigned short* aSrc[8];
  const int colg = ((lane & 7) ^ ((lane >> 3) & 7)) * 8;
#pragma unroll
  for (int i = 0; i < 8; ++i) {
    int r = ab + m_base + wv * 64 + i * 8 + (lane >> 3);
    aSrc[i] = actb + (size_t)r * I_ + colg;
  }
  const int brow = tid >> 2;
  const int bc = (tid & 3) * 16;
  const float* bp = w2 + ((size_t)e * H_ + n0 + brow) * I_ + bc;

#pragma unroll
  for (int i = 0; i < 8; ++i) {
    __builtin_amdgcn_global_load_lds((gp1_t)aSrc[i], (sp3_t)&Ash[0][(wv * 64 + i * 8) * 64], 16, 0, 0);
    aSrc[i] += 64;
  }
  fvec4 r2[4];
#pragma unroll
  for (int j = 0; j < 4; ++j) r2[j] = *(const fvec4*)(bp + j * 4);
  bp += 64;

  f32x4 acc[2][4][2];
#pragma unroll
  for (int mt = 0; mt < 2; ++mt)
#pragma unroll
    for (int mi = 0; mi < 4; ++mi)
#pragma unroll
      for (int ni = 0; ni < 2; ++ni) acc[mt][mi][ni] = (f32x4){0.f, 0.f, 0.f, 0.f};

  const int swz = brow & 7;
  const int c0 = (tid & 3) * 2;
  char* pB = (char*)Bs + brow * 128;

  for (int t = 0; t < I_ / 64; ++t) {
    const int cur = t & 1;
    asm volatile("s_waitcnt vmcnt(0)" ::: "memory");
#pragma unroll
    for (int c = 0; c < 2; ++c) {
      fvec4 lo = r2[c * 2], hi = r2[c * 2 + 1];
      u16x8 v;
      v[0] = f2bf(lo[0]); v[1] = f2bf(lo[1]); v[2] = f2bf(lo[2]); v[3] = f2bf(lo[3]);
      v[4] = f2bf(hi[0]); v[5] = f2bf(hi[1]); v[6] = f2bf(hi[2]); v[7] = f2bf(hi[3]);
      *(u16x8*)(pB + (((c0 + c) ^ swz) << 4)) = v;
    }
    __syncthreads();
    if (t + 1 < I_ / 64) {
#pragma unroll
      for (int i = 0; i < 8; ++i) {
        __builtin_amdgcn_global_load_lds((gp1_t)aSrc[i],
            (sp3_t)&Ash[cur ^ 1][(wv * 64 + i * 8) * 64], 16, 0, 0);
        aSrc[i] += 64;
      }
#pragma unroll
      for (int j = 0; j < 4; ++j) r2[j] = *(const fvec4*)(bp + j * 4);
      bp += 64;
    }
    const unsigned short* Ac = Ash[cur];
#pragma unroll
    for (int kk = 0; kk < 2; ++kk) {
      const int c16 = kk * 4 + (lane >> 4);
      bf16x8 bf[2];
#pragma unroll
      for (int ni = 0; ni < 2; ++ni) {
        int br_ = wn * 32 + ni * 16 + (lane & 15);
        bf[ni] = *(const bf16x8*)((const char*)Bs + br_ * 128 + ((c16 ^ (br_ & 7)) << 4));
      }
#pragma unroll
      for (int mt = 0; mt < 2; ++mt) {
        bf16x8 af[4];
#pragma unroll
        for (int mi = 0; mi < 4; ++mi) {
          int ar = mt * 128 + wm * 64 + mi * 16 + (lane & 15);
          af[mi] = *(const bf16x8*)((const char*)Ac + ar * 128 + ((c16 ^ (ar & 7)) << 4));
        }
#pragma unroll
        for (int mi = 0; mi < 4; ++mi)
#pragma unroll
          for (int ni = 0; ni < 2; ++ni)
            acc[mt][mi][ni] = __builtin_amdgcn_mfma_f32_16x16x32_bf16(af[mi], bf[ni], acc[mt][mi][ni], 0, 0, 0);
      }
    }
    __syncthreads();
  }

#pragma unroll
  for (int mt = 0; mt < 2; ++mt)
#pragma unroll
    for (int mi = 0; mi < 4; ++mi)
#pragma unroll
      for (int ni = 0; ni < 2; ++ni)
#pragma unroll
        for (int j = 0; j < 4; ++j) {
          int row = mt * 128 + wm * 64 + mi * 16 + (lane >> 4) * 4 + j;
          if (m_base + row < count) {
            int col = n0 + wn * 32 + ni * 16 + (lane & 15);
            atomicAdd(&out[(size_t)tokS[row] * H_ + col], gateS[row] * acc[mt][mi][ni][j]);
          }
        }
}

extern "C" void kernel_launch(void* const* d_in, const int* in_sizes, int n_in,
                              void* d_out, int out_size, void* d_ws, size_t ws_size,
                              hipStream_t stream) {
  const float* x  = (const float*)d_in[0];
  const float* gw = (const float*)d_in[1];
  const float* w1 = (const float*)d_in[2];
  const float* w3 = (const float*)d_in[3];
  const float* w2 = (const float*)d_in[4];
  float* out = (float*)d_out;
  char* ws = (char*)d_ws;

  int* cnt = (int*)ws;
  int* base = (int*)(ws + 64);
  int* tokl = (int*)(ws + WS_TOK);
  float* gatel = (float*)(ws + WS_GATE);
  unsigned short* xb = (unsigned short*)(ws + WS_XB);
  unsigned short* actb = (unsigned short*)(ws + WS_ACT);

  (void)hipMemsetAsync(d_out, 0, (size_t)T_ * H_ * sizeof(float), stream);
  (void)hipMemsetAsync(ws, 0, 64, stream);

  cvt_x_kernel<<<(T_ * H_ / 4 + 255) / 256, 256, 0, stream>>>(x, xb);
  router_kernel<<<T_ / 4, 256, 0, stream>>>(x, gw, cnt, tokl, gatel);
  prefix_kernel<<<1, 64, 0, stream>>>(cnt, base);
  ffn1_kernel<<<dim3(I_ / 64, 4, E_), 256, 0, stream>>>(xb, w1, w3, cnt, base, tokl, actb);
  ffn2_kernel<<<dim3(H_ / 64, 4, E_), 256, 0, stream>>>(actb, w2, cnt, base, tokl, gatel, out);
}